// Round 4
// baseline (116.328 us; speedup 1.0000x reference)
//
#include <hip/hip_runtime.h>
#include <math.h>

#define N_V 12288
#define D_F 32
#define N_E 196608
#define KNN 6
#define EPSF 1e-12f

#define SEGS 16
#define JSEG (N_V / SEGS)          // 768 candidate columns per segment
#define SUBTILES (JSEG / 16)       // 48 j-subtiles per segment
#define BLOCK_T 512                // 8 waves
#define ROWS_PER_BLOCK 256         // 8 waves x 32 query rows
#define ROW_BLOCKS (N_V / ROWS_PER_BLOCK)  // 48 -> grid 48 x 16 = 768 blocks (3/CU, 1 round)
#define NKEEP 5                    // top-5 non-self keys kept per (row, seg)
#define NEGF -3.0e38f

#define LDS_BYTES (JSEG * 64)      // 49152 B = 48K exactly: A tiles only (3 blocks/CU safe)

typedef __bf16 bf16x8 __attribute__((ext_vector_type(8)));
typedef float f32x4 __attribute__((ext_vector_type(4)));

static_assert(N_V % ROWS_PER_BLOCK == 0, "");
static_assert(SUBTILES % 8 == 0, "");

__device__ __forceinline__ unsigned short f2bf(float f) {
    unsigned u = __builtin_bit_cast(unsigned, f);
    unsigned r = u + 0x7fffu + ((u >> 16) & 1u);   // RNE
    return (unsigned short)(r >> 16);
}

__device__ __forceinline__ float bfu2f(unsigned hw_lo16) {   // low 16 bits -> float
    return __builtin_bit_cast(float, hw_lo16 << 16);
}
__device__ __forceinline__ float bfhi2f(unsigned u) {        // high 16 bits -> float
    return __builtin_bit_cast(float, u & 0xffff0000u);
}

// descending sorted 5-list insert using ONLY full-rate VOP2 min/max
// (v_med3_f32 appears to be sub-rate on gfx950: three structurally different
//  schedules all pinned at the same VALU-busy-time with the med3 version).
// y_i = max(s_i, min(s_{i-1}, nv)); depth 2, 9 ops.
__device__ __forceinline__ void ins5(float s[NKEEP], float nv) {
    const float m1 = fminf(s[0], nv);
    const float m2 = fminf(s[1], nv);
    const float m3 = fminf(s[2], nv);
    const float m4 = fminf(s[3], nv);
    s[0] = fmaxf(s[0], nv);
    s[1] = fmaxf(s[1], m1);
    s[2] = fmaxf(s[2], m2);
    s[3] = fmaxf(s[3], m3);
    s[4] = fmaxf(s[4], m4);
}

// ---------- kernel 0: bf16 convert + msq(-0.5*sq), 8 threads/row ----------
__global__ __launch_bounds__(256) void prep_kernel(const float* __restrict__ x,
                                                   unsigned short* __restrict__ xb,
                                                   float* __restrict__ msq) {
    const int gid = blockIdx.x * 256 + threadIdx.x;   // 0..98303
    const int row = gid >> 3;
    const int h = gid & 7;
    float4 p = ((const float4*)(x + (size_t)row * D_F))[h];
    float s = p.x * p.x + p.y * p.y + p.z * p.z + p.w * p.w;
    s += __shfl_xor(s, 1, 64);
    s += __shfl_xor(s, 2, 64);
    s += __shfl_xor(s, 4, 64);
    const unsigned lo = (unsigned)f2bf(p.x) | ((unsigned)f2bf(p.y) << 16);
    const unsigned hi = (unsigned)f2bf(p.z) | ((unsigned)f2bf(p.w) << 16);
    ((uint2*)xb)[gid] = make_uint2(lo, hi);
    if (h == 0) msq[row] = -0.5f * s;
}

// ---------- kernel 1: MFMA gram + per-row top-5 (non-self) keys ----------
// A staged in LDS (48K exactly), fragment-linear: lds[it*1024 + lane*16].
// msq read from global (L2-hot, VMEM pipe — zero VALU cost, keeps LDS at 48K
// so 3 blocks/CU survive any LDS allocation granularity).
// Inner loop: ds_read_b128 at base+imm, global 16B m-load, 2 MFMA, 8x ins5.
__global__ __launch_bounds__(BLOCK_T, 6) void topk_mfma(
    const unsigned short* __restrict__ xb, const float* __restrict__ msq,
    float* __restrict__ cand) {
    __shared__ alignas(16) char lds[LDS_BYTES];
    const int t = threadIdx.x;
    const int wave = t >> 6;
    const int lane = t & 63;
    const int quad = lane >> 4;
    const int l16 = lane & 15;

    const int rowbase = blockIdx.x * ROWS_PER_BLOCK + wave * 32;
    const int seg = blockIdx.y;
    const int j0 = seg * JSEG;

    // ---- stage segment A-tiles into LDS (each wave: 6 subtiles) ----
#pragma unroll
    for (int k = 0; k < SUBTILES / 8; ++k) {
        const int it = wave + 8 * k;
        const uint4 val = *((const uint4*)(xb + (size_t)(j0 + it * 16 + l16) * D_F) + quad);
        *((uint4*)(lds + it * 1024) + lane) = val;
    }

    // B fragments: query rows, register-resident (global loads, overlap staging)
    bf16x8 bfrag0 = *reinterpret_cast<const bf16x8*>(
        xb + (size_t)(rowbase + l16) * D_F + quad * 8);
    bf16x8 bfrag1 = *reinterpret_cast<const bf16x8*>(
        xb + (size_t)(rowbase + 16 + l16) * D_F + quad * 8);

    __syncthreads();

    float tk0[NKEEP], tk1[NKEEP];
#pragma unroll
    for (int k = 0; k < NKEEP; ++k) { tk0[k] = NEGF; tk1[k] = NEGF; }

    // lane's self position inside a matching subtile: quad*4+reg == l16
    const int selfreg = (quad == (l16 >> 2)) ? (l16 & 3) : 8;
    const int rb0 = rowbase;
    const int rb1 = rowbase + 16;

    const char* aBase = lds + lane * 16;
    const float* mBase = msq + j0 + quad * 4;

#pragma unroll
    for (int it = 0; it < SUBTILES; ++it) {
        const bf16x8 a = *reinterpret_cast<const bf16x8*>(aBase + it * 1024);
        const f32x4 m = *reinterpret_cast<const f32x4*>(mBase + it * 16);

        f32x4 c0 = __builtin_amdgcn_mfma_f32_16x16x32_bf16(a, bfrag0, m, 0, 0, 0);
        f32x4 c1 = __builtin_amdgcn_mfma_f32_16x16x32_bf16(a, bfrag1, m, 0, 0, 0);

        const int jt = j0 + (it << 4);
        if (jt == rb0) {   // wave-uniform: this subtile contains rt=0 self diag
            c0[0] = (selfreg == 0) ? NEGF : c0[0];
            c0[1] = (selfreg == 1) ? NEGF : c0[1];
            c0[2] = (selfreg == 2) ? NEGF : c0[2];
            c0[3] = (selfreg == 3) ? NEGF : c0[3];
        }
        if (jt == rb1) {   // wave-uniform: this subtile contains rt=1 self diag
            c1[0] = (selfreg == 0) ? NEGF : c1[0];
            c1[1] = (selfreg == 1) ? NEGF : c1[1];
            c1[2] = (selfreg == 2) ? NEGF : c1[2];
            c1[3] = (selfreg == 3) ? NEGF : c1[3];
        }

        ins5(tk0, c0[0]); ins5(tk0, c0[1]); ins5(tk0, c0[2]); ins5(tk0, c0[3]);
        ins5(tk1, c1[0]); ins5(tk1, c1[1]); ins5(tk1, c1[2]); ins5(tk1, c1[3]);
    }

    // ---- cross-quad merge via shuffles (row's lists live in 4 quads, same l16) ----
#pragma unroll
    for (int rnd = 0; rnd < 2; ++rnd) {
        const int mask = 16 << rnd;
        float b[NKEEP];
#pragma unroll
        for (int k = 0; k < NKEEP; ++k) b[k] = __shfl_xor(tk0[k], mask, 64);
#pragma unroll
        for (int k = 0; k < NKEEP; ++k) ins5(tk0, b[k]);
#pragma unroll
        for (int k = 0; k < NKEEP; ++k) b[k] = __shfl_xor(tk1[k], mask, 64);
#pragma unroll
        for (int k = 0; k < NKEEP; ++k) ins5(tk1, b[k]);
    }

    if (quad == 0) {
        const int g0 = rowbase + l16;
        float* dst0 = cand + ((size_t)g0 * SEGS + seg) * NKEEP;
#pragma unroll
        for (int k = 0; k < NKEEP; ++k) dst0[k] = tk0[k];
        const int g1 = rowbase + 16 + l16;
        float* dst1 = cand + ((size_t)g1 * SEGS + seg) * NKEEP;
#pragma unroll
        for (int k = 0; k < NKEEP; ++k) dst1[k] = tk1[k];
    }
}

// ---------- kernel 2: merge per-segment keys -> v, 4 threads/row ----------
__global__ __launch_bounds__(256) void merge_v(const float* __restrict__ cand,
                                               const float* __restrict__ msq,
                                               float* __restrict__ v,
                                               float* __restrict__ out) {
    const int gid = blockIdx.x * 256 + threadIdx.x;   // 0..49151
    const int row = gid >> 2;
    const int h = gid & 3;
    const float4* c = (const float4*)(cand + (size_t)row * (SEGS * NKEEP));  // 20 x float4
    float mk[NKEEP];
#pragma unroll
    for (int k = 0; k < NKEEP; ++k) mk[k] = NEGF;
#pragma unroll
    for (int s = 0; s < 5; ++s) {
        float4 q = c[h + 4 * s];
        ins5(mk, q.x); ins5(mk, q.y); ins5(mk, q.z); ins5(mk, q.w);
    }
    // merge across the 4 lanes of this row (consecutive lanes, same wave)
#pragma unroll
    for (int rnd = 0; rnd < 2; ++rnd) {
        const int mask = 1 << rnd;
        float b[NKEEP];
#pragma unroll
        for (int k = 0; k < NKEEP; ++k) b[k] = __shfl_xor(mk[k], mask, 64);
#pragma unroll
        for (int k = 0; k < NKEEP; ++k) ins5(mk, b[k]);
    }
    if (h == 0) {
        const float msqi = msq[row];
        float ssum = 0.f;
#pragma unroll
        for (int m = 0; m < NKEEP; ++m) {
            const float d2 = -2.0f * (mk[m] + msqi);   // sq_i - 2*key
            ssum += expf(-sqrtf(fmaxf(d2, EPSF)));
        }
        const float vi = 1.0f - ssum / (float)KNN;
        v[row] = vi;
        out[2 * row] = vi;
        out[2 * row + 1] = 0.0f;
    }
}

// ---------- kernel 3: edge filtration (bf16 gather: 1 line per row) ----------
__global__ __launch_bounds__(256) void edge_kernel(const unsigned short* __restrict__ xb,
                                                   const int* __restrict__ ei,
                                                   const float* __restrict__ v,
                                                   float* __restrict__ out) {
    int e = blockIdx.x * 256 + threadIdx.x;
    if (e >= N_E) return;
    const int u = ei[e];
    const int w = ei[N_E + e];
    const uint4* xu = (const uint4*)(xb + (size_t)u * D_F);
    const uint4* xw = (const uint4*)(xb + (size_t)w * D_F);
    float acc = 0.f;
#pragma unroll
    for (int d = 0; d < 4; ++d) {
        const uint4 p = xu[d];
        const uint4 q = xw[d];
#pragma unroll
        for (int c = 0; c < 4; ++c) {
            const unsigned pu = (&p.x)[c];
            const unsigned qu = (&q.x)[c];
            const float d0 = bfu2f(pu) - bfu2f(qu);
            const float d1 = bfhi2f(pu) - bfhi2f(qu);
            acc = fmaf(d0, d0, acc);
            acc = fmaf(d1, d1, acc);
        }
    }
    const float enorm = sqrtf(fmaxf(acc, EPSF));
    const float ey = 1.0f - expf(-enorm);
    const float ev = fmaxf(v[u], v[w]);
    out[2 * (N_V + e) + 0] = ev;
    out[2 * (N_V + e) + 1] = ey;
}

extern "C" void kernel_launch(void* const* d_in, const int* in_sizes, int n_in,
                              void* d_out, int out_size, void* d_ws, size_t ws_size,
                              hipStream_t stream) {
    const float* x = (const float*)d_in[0];
    const int* ei = (const int*)d_in[1];
    float* out = (float*)d_out;
    char* ws = (char*)d_ws;

    unsigned short* xb = (unsigned short*)ws;                  // 786432 B
    float* msq = (float*)(ws + 786432);                        // 49152 B
    float* v   = (float*)(ws + 786432 + 49152);                // 49152 B
    float* cand = (float*)(ws + 786432 + 2 * 49152);           // 12288*16*5*4 = 3932160 B

    prep_kernel<<<(N_V * 8) / 256, 256, 0, stream>>>(x, xb, msq);

    dim3 g1(ROW_BLOCKS, SEGS);
    topk_mfma<<<g1, BLOCK_T, 0, stream>>>(xb, msq, cand);

    merge_v<<<(N_V * 4) / 256, 256, 0, stream>>>(cand, msq, v, out);

    edge_kernel<<<N_E / 256, 256, 0, stream>>>(xb, ei, v, out);
}

// Round 5
// 108.294 us; speedup vs baseline: 1.0742x; 1.0742x over previous
//
#include <hip/hip_runtime.h>
#include <math.h>

#define N_V 12288
#define D_F 32
#define N_E 196608
#define KNN 6
#define EPSF 1e-12f

#define SEGS 16
#define JSEG (N_V / SEGS)          // 768 candidate columns per segment
#define SUBTILES (JSEG / 16)       // 48 j-subtiles per segment
#define BLOCK_T 512                // 8 waves
#define ROWS_PER_BLOCK 256         // 8 waves x 32 query rows
#define ROW_BLOCKS (N_V / ROWS_PER_BLOCK)  // 48 -> grid 48 x 16 = 768 blocks
#define NKEEP 5                    // top-5 non-self keys kept per (row, seg)
#define NEGF -3.0e38f

#define A_BYTES (JSEG * 64)        // 49152: A tiles, fragment-linear
#define M_OFF A_BYTES              // msq region at 49152
#define LDS_BYTES (A_BYTES + JSEG * 4)  // 52224

typedef __bf16 bf16x8 __attribute__((ext_vector_type(8)));
typedef float f32x4 __attribute__((ext_vector_type(4)));

static_assert(N_V % ROWS_PER_BLOCK == 0, "");
static_assert(SUBTILES % 8 == 0, "");

__device__ __forceinline__ unsigned short f2bf(float f) {
    unsigned u = __builtin_bit_cast(unsigned, f);
    unsigned r = u + 0x7fffu + ((u >> 16) & 1u);   // RNE
    return (unsigned short)(r >> 16);
}

__device__ __forceinline__ float bfu2f(unsigned hw_lo16) {   // low 16 bits -> float
    return __builtin_bit_cast(float, hw_lo16 << 16);
}
__device__ __forceinline__ float bfhi2f(unsigned u) {        // high 16 bits -> float
    return __builtin_bit_cast(float, u & 0xffff0000u);
}

// pack 8 f32 -> bf16x8 (RNE)
__device__ __forceinline__ bf16x8 pack8(float4 a, float4 b) {
    uint4 w;
    w.x = (unsigned)f2bf(a.x) | ((unsigned)f2bf(a.y) << 16);
    w.y = (unsigned)f2bf(a.z) | ((unsigned)f2bf(a.w) << 16);
    w.z = (unsigned)f2bf(b.x) | ((unsigned)f2bf(b.y) << 16);
    w.w = (unsigned)f2bf(b.z) | ((unsigned)f2bf(b.w) << 16);
    return __builtin_bit_cast(bf16x8, w);
}

// descending sorted 5-list insert: 1 max + 4 med3 (med3 is full-rate; R4 proved
// the 9-op min/max variant strictly worse)
__device__ __forceinline__ void ins5(float s[NKEEP], float nv) {
    float y0 = fmaxf(s[0], nv);
    float y1 = __builtin_amdgcn_fmed3f(s[0], s[1], nv);
    float y2 = __builtin_amdgcn_fmed3f(s[1], s[2], nv);
    float y3 = __builtin_amdgcn_fmed3f(s[2], s[3], nv);
    float y4 = __builtin_amdgcn_fmed3f(s[3], s[4], nv);
    s[0] = y0; s[1] = y1; s[2] = y2; s[3] = y3; s[4] = y4;
}

// ---------- kernel 1 (fused prep+topk): MFMA gram + per-row top-5 ----------
// Each block stages its 768-col segment from x (f32), converting to bf16 into
// LDS fragment-linear and computing msq into LDS. seg==0 blocks also write the
// bf16 matrix xb to global for edge_kernel. Inner loop is a pinned 1-deep
// software pipeline: MFMA(it+1) is forced ABOVE the selects of (it) via a tied
// empty asm (selects data-depend on its outputs, it data-depends on the next
// MFMA) so MFMA latency hides under the 40 select ops. Dual tk lists (even/odd
// subtiles) halve the loop-carried select dependency depth.
__global__ __launch_bounds__(BLOCK_T, 6) void topk_mfma(
    const float* __restrict__ x, unsigned short* __restrict__ xb,
    float* __restrict__ cand) {
    __shared__ alignas(16) char lds[LDS_BYTES];
    const int t = threadIdx.x;
    const int wave = t >> 6;
    const int lane = t & 63;
    const int quad = lane >> 4;
    const int l16 = lane & 15;

    const int rowbase = blockIdx.x * ROWS_PER_BLOCK + wave * 32;
    const int seg = blockIdx.y;
    const int j0 = seg * JSEG;

    // ---- stage segment A-tiles into LDS (each wave: 6 subtiles), f32->bf16,
    //      and per-col msq = -0.5*||x_j||^2 ----
#pragma unroll
    for (int k = 0; k < SUBTILES / 8; ++k) {
        const int it = wave + 8 * k;
        const int j = j0 + it * 16 + l16;
        const float4* xp = (const float4*)(x + (size_t)j * D_F);
        const float4 pA = xp[quad * 2];
        const float4 pB = xp[quad * 2 + 1];
        float s = pA.x * pA.x + pA.y * pA.y + pA.z * pA.z + pA.w * pA.w
                + pB.x * pB.x + pB.y * pB.y + pB.z * pB.z + pB.w * pB.w;
        s += __shfl_xor(s, 16, 64);
        s += __shfl_xor(s, 32, 64);
        const bf16x8 pk = pack8(pA, pB);
        *((uint4*)(lds + it * 1024) + lane) = __builtin_bit_cast(uint4, pk);
        if (quad == 0)
            *(float*)(lds + M_OFF + (size_t)(it * 16 + l16) * 4) = -0.5f * s;
    }

    // ---- B fragments: query rows, converted in-register from x ----
    const float4* q0p = (const float4*)(x + (size_t)(rowbase + l16) * D_F);
    const float4* q1p = (const float4*)(x + (size_t)(rowbase + 16 + l16) * D_F);
    const bf16x8 bfrag0 = pack8(q0p[quad * 2], q0p[quad * 2 + 1]);
    const bf16x8 bfrag1 = pack8(q1p[quad * 2], q1p[quad * 2 + 1]);

    // seg==0 blocks publish the bf16 matrix for edge_kernel (covers all rows)
    if (seg == 0) {
        *(uint4*)(xb + (size_t)(rowbase + l16) * D_F + quad * 8) =
            __builtin_bit_cast(uint4, bfrag0);
        *(uint4*)(xb + (size_t)(rowbase + 16 + l16) * D_F + quad * 8) =
            __builtin_bit_cast(uint4, bfrag1);
    }

    __syncthreads();

    // dual lists per rt: evens -> A, odds -> B (4 independent insert chains)
    float tkA0[NKEEP], tkB0[NKEEP], tkA1[NKEEP], tkB1[NKEEP];
#pragma unroll
    for (int k = 0; k < NKEEP; ++k) {
        tkA0[k] = NEGF; tkB0[k] = NEGF; tkA1[k] = NEGF; tkB1[k] = NEGF;
    }

    // lane's self position inside a matching subtile: quad*4+reg == l16
    const int selfreg = (quad == (l16 >> 2)) ? (l16 & 3) : 8;
    const int rb0 = rowbase;
    const int rb1 = rowbase + 16;

    const char* aBase = lds + lane * 16;
    const char* mBase = lds + M_OFF + quad * 16;

#define LDA(i) (*reinterpret_cast<const bf16x8*>(aBase + (i) * 1024))
#define LDM(i) (*reinterpret_cast<const f32x4*>(mBase + (i) * 64))

    // prologue: subtile 0 computed; subtile 1 operands in regs
    bf16x8 a_nx = LDA(0);
    f32x4 m_nx = LDM(0);
    f32x4 c0 = __builtin_amdgcn_mfma_f32_16x16x32_bf16(a_nx, bfrag0, m_nx, 0, 0, 0);
    f32x4 c1 = __builtin_amdgcn_mfma_f32_16x16x32_bf16(a_nx, bfrag1, m_nx, 0, 0, 0);
    a_nx = LDA(1);
    m_nx = LDM(1);

#pragma unroll
    for (int it = 0; it < SUBTILES - 1; ++it) {
        const int itn = (it + 2 < SUBTILES) ? it + 2 : SUBTILES - 1;
        const bf16x8 a_pf = LDA(itn);
        const f32x4 m_pf = LDM(itn);

        // next subtile's MFMAs (operands loaded one iteration ago)
        f32x4 cn0 = __builtin_amdgcn_mfma_f32_16x16x32_bf16(a_nx, bfrag0, m_nx, 0, 0, 0);
        f32x4 cn1 = __builtin_amdgcn_mfma_f32_16x16x32_bf16(a_nx, bfrag1, m_nx, 0, 0, 0);

        // order pin: selects below depend on the asm outputs; the asm depends
        // on cn0/cn1 -> MFMA(it+1) must issue before the select block of (it).
        asm volatile(""
            : "+v"(c0[0]), "+v"(c0[1]), "+v"(c0[2]), "+v"(c0[3]),
              "+v"(c1[0]), "+v"(c1[1]), "+v"(c1[2]), "+v"(c1[3])
            : "v"(cn0[0]), "v"(cn1[0]));

        const int jt = j0 + (it << 4);
        if (jt == rb0) {   // wave-uniform: subtile contains rt=0 self diag
            c0[0] = (selfreg == 0) ? NEGF : c0[0];
            c0[1] = (selfreg == 1) ? NEGF : c0[1];
            c0[2] = (selfreg == 2) ? NEGF : c0[2];
            c0[3] = (selfreg == 3) ? NEGF : c0[3];
        }
        if (jt == rb1) {   // wave-uniform: subtile contains rt=1 self diag
            c1[0] = (selfreg == 0) ? NEGF : c1[0];
            c1[1] = (selfreg == 1) ? NEGF : c1[1];
            c1[2] = (selfreg == 2) ? NEGF : c1[2];
            c1[3] = (selfreg == 3) ? NEGF : c1[3];
        }

        if (it & 1) {
            ins5(tkB0, c0[0]); ins5(tkB0, c0[1]); ins5(tkB0, c0[2]); ins5(tkB0, c0[3]);
            ins5(tkB1, c1[0]); ins5(tkB1, c1[1]); ins5(tkB1, c1[2]); ins5(tkB1, c1[3]);
        } else {
            ins5(tkA0, c0[0]); ins5(tkA0, c0[1]); ins5(tkA0, c0[2]); ins5(tkA0, c0[3]);
            ins5(tkA1, c1[0]); ins5(tkA1, c1[1]); ins5(tkA1, c1[2]); ins5(tkA1, c1[3]);
        }

        c0 = cn0; c1 = cn1;
        a_nx = a_pf; m_nx = m_pf;
    }

    // epilogue: select subtile 47 (odd -> B lists)
    {
        const int it = SUBTILES - 1;
        const int jt = j0 + (it << 4);
        if (jt == rb0) {
            c0[0] = (selfreg == 0) ? NEGF : c0[0];
            c0[1] = (selfreg == 1) ? NEGF : c0[1];
            c0[2] = (selfreg == 2) ? NEGF : c0[2];
            c0[3] = (selfreg == 3) ? NEGF : c0[3];
        }
        if (jt == rb1) {
            c1[0] = (selfreg == 0) ? NEGF : c1[0];
            c1[1] = (selfreg == 1) ? NEGF : c1[1];
            c1[2] = (selfreg == 2) ? NEGF : c1[2];
            c1[3] = (selfreg == 3) ? NEGF : c1[3];
        }
        ins5(tkB0, c0[0]); ins5(tkB0, c0[1]); ins5(tkB0, c0[2]); ins5(tkB0, c0[3]);
        ins5(tkB1, c1[0]); ins5(tkB1, c1[1]); ins5(tkB1, c1[2]); ins5(tkB1, c1[3]);
    }

    // merge B lists into A lists
#pragma unroll
    for (int k = 0; k < NKEEP; ++k) ins5(tkA0, tkB0[k]);
#pragma unroll
    for (int k = 0; k < NKEEP; ++k) ins5(tkA1, tkB1[k]);

    // ---- cross-quad merge via shuffles (row's lists live in 4 quads, same l16) ----
#pragma unroll
    for (int rnd = 0; rnd < 2; ++rnd) {
        const int mask = 16 << rnd;
        float b[NKEEP];
#pragma unroll
        for (int k = 0; k < NKEEP; ++k) b[k] = __shfl_xor(tkA0[k], mask, 64);
#pragma unroll
        for (int k = 0; k < NKEEP; ++k) ins5(tkA0, b[k]);
#pragma unroll
        for (int k = 0; k < NKEEP; ++k) b[k] = __shfl_xor(tkA1[k], mask, 64);
#pragma unroll
        for (int k = 0; k < NKEEP; ++k) ins5(tkA1, b[k]);
    }

    if (quad == 0) {
        const int g0 = rowbase + l16;
        float* dst0 = cand + ((size_t)g0 * SEGS + seg) * NKEEP;
#pragma unroll
        for (int k = 0; k < NKEEP; ++k) dst0[k] = tkA0[k];
        const int g1 = rowbase + 16 + l16;
        float* dst1 = cand + ((size_t)g1 * SEGS + seg) * NKEEP;
#pragma unroll
        for (int k = 0; k < NKEEP; ++k) dst1[k] = tkA1[k];
    }
#undef LDA
#undef LDM
}

// ---------- kernel 2: merge per-segment keys -> v, 4 threads/row ----------
__global__ __launch_bounds__(256) void merge_v(const float* __restrict__ cand,
                                               const float* __restrict__ x,
                                               float* __restrict__ v,
                                               float* __restrict__ out) {
    const int gid = blockIdx.x * 256 + threadIdx.x;   // 0..49151
    const int row = gid >> 2;
    const int h = gid & 3;
    const float4* c = (const float4*)(cand + (size_t)row * (SEGS * NKEEP));  // 20 x float4
    float mk[NKEEP];
#pragma unroll
    for (int k = 0; k < NKEEP; ++k) mk[k] = NEGF;
#pragma unroll
    for (int s = 0; s < 5; ++s) {
        float4 q = c[h + 4 * s];
        ins5(mk, q.x); ins5(mk, q.y); ins5(mk, q.z); ins5(mk, q.w);
    }
    // own msq from x: each lane sums its 8-elem chunk, reduce across 4 lanes
    const float4* xp = (const float4*)(x + (size_t)row * D_F);
    const float4 pA = xp[h * 2];
    const float4 pB = xp[h * 2 + 1];
    float sq = pA.x * pA.x + pA.y * pA.y + pA.z * pA.z + pA.w * pA.w
             + pB.x * pB.x + pB.y * pB.y + pB.z * pB.z + pB.w * pB.w;
    sq += __shfl_xor(sq, 1, 64);
    sq += __shfl_xor(sq, 2, 64);
    // merge across the 4 lanes of this row (consecutive lanes, same wave)
#pragma unroll
    for (int rnd = 0; rnd < 2; ++rnd) {
        const int mask = 1 << rnd;
        float b[NKEEP];
#pragma unroll
        for (int k = 0; k < NKEEP; ++k) b[k] = __shfl_xor(mk[k], mask, 64);
#pragma unroll
        for (int k = 0; k < NKEEP; ++k) ins5(mk, b[k]);
    }
    if (h == 0) {
        const float msqi = -0.5f * sq;
        float ssum = 0.f;
#pragma unroll
        for (int m = 0; m < NKEEP; ++m) {
            const float d2 = -2.0f * (mk[m] + msqi);   // sq_i - 2*key
            ssum += expf(-sqrtf(fmaxf(d2, EPSF)));
        }
        const float vi = 1.0f - ssum / (float)KNN;
        v[row] = vi;
        out[2 * row] = vi;
        out[2 * row + 1] = 0.0f;
    }
}

// ---------- kernel 3: edge filtration (bf16 gather: 1 line per row) ----------
__global__ __launch_bounds__(256) void edge_kernel(const unsigned short* __restrict__ xb,
                                                   const int* __restrict__ ei,
                                                   const float* __restrict__ v,
                                                   float* __restrict__ out) {
    int e = blockIdx.x * 256 + threadIdx.x;
    if (e >= N_E) return;
    const int u = ei[e];
    const int w = ei[N_E + e];
    const uint4* xu = (const uint4*)(xb + (size_t)u * D_F);
    const uint4* xw = (const uint4*)(xb + (size_t)w * D_F);
    float acc = 0.f;
#pragma unroll
    for (int d = 0; d < 4; ++d) {
        const uint4 p = xu[d];
        const uint4 q = xw[d];
#pragma unroll
        for (int c = 0; c < 4; ++c) {
            const unsigned pu = (&p.x)[c];
            const unsigned qu = (&q.x)[c];
            const float d0 = bfu2f(pu) - bfu2f(qu);
            const float d1 = bfhi2f(pu) - bfhi2f(qu);
            acc = fmaf(d0, d0, acc);
            acc = fmaf(d1, d1, acc);
        }
    }
    const float enorm = sqrtf(fmaxf(acc, EPSF));
    const float ey = 1.0f - expf(-enorm);
    const float ev = fmaxf(v[u], v[w]);
    out[2 * (N_V + e) + 0] = ev;
    out[2 * (N_V + e) + 1] = ey;
}

extern "C" void kernel_launch(void* const* d_in, const int* in_sizes, int n_in,
                              void* d_out, int out_size, void* d_ws, size_t ws_size,
                              hipStream_t stream) {
    const float* x = (const float*)d_in[0];
    const int* ei = (const int*)d_in[1];
    float* out = (float*)d_out;
    char* ws = (char*)d_ws;

    unsigned short* xb = (unsigned short*)ws;                  // 786432 B
    float* v   = (float*)(ws + 786432);                        // 49152 B
    float* cand = (float*)(ws + 786432 + 49152);               // 12288*16*5*4 = 3932160 B

    dim3 g1(ROW_BLOCKS, SEGS);
    topk_mfma<<<g1, BLOCK_T, 0, stream>>>(x, xb, cand);

    merge_v<<<(N_V * 4) / 256, 256, 0, stream>>>(cand, x, v, out);

    edge_kernel<<<N_E / 256, 256, 0, stream>>>(xb, ei, v, out);
}